// Round 14
// baseline (336.467 us; speedup 1.0000x reference)
//
#include <hip/hip_runtime.h>
#include <math.h>

// GATv2 3-layer forward, MI355X.
// R13: (a) revert count/fill to R11 config (single-pass rank-capture count +
// XCD-sliced rank-based fill — R12's cursor/XCD-count variant was ~4us worse);
// keep R12's harmless fusions (wt_build+zero, scan2, finalize sans cursor).
// (b) split-4 edge partitioning for the layer-3 agg (16 lanes/node, 2-round
// shfl merge): per-lane serial chain 4.5->2.3 edges, 2x waves. Probes whether
// agg3 is still latency-bound or at the ~2.5 TB/s random-gather wall.
// R10 degree-sort + fp16 staging, R9 MFMA GEMM, R7 no-max softmax agg kept.
// N=100000, E=800000 (+N self loops), Fin=64, H=4, C=16/16/32.

#define HEADS 4
#define NSLOPE 0.2f

typedef __attribute__((ext_vector_type(8))) _Float16 half8;
typedef __attribute__((ext_vector_type(2))) _Float16 h2;
typedef __attribute__((ext_vector_type(4))) float f32x4;

union H8 {
  half8 v;
  h2 h[4];
};

// ---------------------------------------------------------------------------
// One-time: build fp16 W^T for all 3 layers (wt[c*64+k] = W[k][c], combined
// [Wl | Wr] cols) + zero deg/hist (replaces 2 memsets).
__global__ __launch_bounds__(256) void wt_build_zero_kernel(
    const float* __restrict__ W1l, const float* __restrict__ W1r,
    const float* __restrict__ W2l, const float* __restrict__ W2r,
    const float* __restrict__ W3l, const float* __restrict__ W3r,
    _Float16* __restrict__ wt1, _Float16* __restrict__ wt2,
    _Float16* __restrict__ wt3, int* __restrict__ deg, int* __restrict__ hist,
    int N) {
  const int tid = blockIdx.x * 256 + threadIdx.x;
  for (int i = tid; i < N; i += gridDim.x * 256) deg[i] = 0;
  if (tid < 64) hist[tid] = 0;
  int i = tid;
  const float *Wl, *Wr;
  _Float16* wt;
  int COLS;
  if (i < 8192) {
    Wl = W1l; Wr = W1r; wt = wt1; COLS = 64;
  } else if (i < 16384) {
    i -= 8192; Wl = W2l; Wr = W2r; wt = wt2; COLS = 64;
  } else if (i < 32768) {
    i -= 16384; Wl = W3l; Wr = W3r; wt = wt3; COLS = 128;
  } else {
    return;
  }
  const int c = i >> 6, k = i & 63;
  const float v = (c < COLS) ? Wl[k * COLS + c] : Wr[k * COLS + (c - COLS)];
  wt[i] = (_Float16)v;
}

// ---------------------------------------------------------------------------
// MFMA GEMM: [xl | xr] (both fp16) = in @ [Wl | Wr], K=64, via
// mfma_f32_16x16x32_f16. Block: 64 rows x 128 combined cols, 4 waves.
// FP32IN: layer-1 input is fp32; layers 2-3 input (h) is fp16.
// A-frag: A[m=lane&15][k=quad*8+j]; B-frag: B[k=quad*8+j][n=lane&15];
// C/D: col=lane&15, row=quad*4+reg (m89-verified mapping).
template <int TOTAL, bool FP32IN>
__global__ __launch_bounds__(256) void gemm_mfma_kernel(
    const void* __restrict__ in_v, const _Float16* __restrict__ wt,
    _Float16* __restrict__ xl, _Float16* __restrict__ xr, int N) {
  constexpr int COLS = TOTAL / 2;
  __shared__ _Float16 xsh[64][72];   // A tile [m][k]
  __shared__ _Float16 bsh[128][72];  // B tile [n][k] (wt slice)
  const int row0 = blockIdx.x * 64;
  const int bn0 = blockIdx.y * 128;
  const int t = threadIdx.x;

  // stage A: thread owns row t&63, k-range (t>>6)*16..+15
  {
    const int r = t & 63, kq = t >> 6;
    const int row = row0 + r;
    half8 h0, h1;
    if (row < N) {
      if constexpr (FP32IN) {
        const float* inf = (const float*)in_v;
        const float4* src = (const float4*)(inf + (size_t)row * 64 + kq * 16);
        const float4 q0 = src[0], q1 = src[1], q2 = src[2], q3 = src[3];
        h0[0] = (_Float16)q0.x; h0[1] = (_Float16)q0.y;
        h0[2] = (_Float16)q0.z; h0[3] = (_Float16)q0.w;
        h0[4] = (_Float16)q1.x; h0[5] = (_Float16)q1.y;
        h0[6] = (_Float16)q1.z; h0[7] = (_Float16)q1.w;
        h1[0] = (_Float16)q2.x; h1[1] = (_Float16)q2.y;
        h1[2] = (_Float16)q2.z; h1[3] = (_Float16)q2.w;
        h1[4] = (_Float16)q3.x; h1[5] = (_Float16)q3.y;
        h1[6] = (_Float16)q3.z; h1[7] = (_Float16)q3.w;
      } else {
        const _Float16* inh = (const _Float16*)in_v;
        const half8* src = (const half8*)(inh + (size_t)row * 64 + kq * 16);
        h0 = src[0];
        h1 = src[1];
      }
    } else {
#pragma unroll
      for (int j = 0; j < 8; j++) {
        h0[j] = (_Float16)0.f;
        h1[j] = (_Float16)0.f;
      }
    }
    *(half8*)&xsh[r][kq * 16] = h0;
    *(half8*)&xsh[r][kq * 16 + 8] = h1;
  }
  // stage B: 128 wt rows x 64 halves; thread t copies 32 halves of row t>>1
  {
    const int rr = t >> 1, hh = t & 1;
    const half8* src = (const half8*)(wt + ((size_t)(bn0 + rr) << 6) + hh * 32);
    const half8 b0 = src[0], b1 = src[1], b2 = src[2], b3 = src[3];
    half8* dst = (half8*)&bsh[rr][hh * 32];
    dst[0] = b0; dst[1] = b1; dst[2] = b2; dst[3] = b3;
  }
  __syncthreads();

  const int lane = t & 63, w = t >> 6;
  const int lm = lane & 15, lq = lane >> 4;
  const int m0 = w * 16;
  const half8 a0 = *(const half8*)&xsh[m0 + lm][lq * 8];
  const half8 a1 = *(const half8*)&xsh[m0 + lm][32 + lq * 8];
  f32x4 acc[8];
#pragma unroll
  for (int nt = 0; nt < 8; nt++) {
    const half8 b0 = *(const half8*)&bsh[nt * 16 + lm][lq * 8];
    const half8 b1 = *(const half8*)&bsh[nt * 16 + lm][32 + lq * 8];
    f32x4 c = {0.f, 0.f, 0.f, 0.f};
    c = __builtin_amdgcn_mfma_f32_16x16x32_f16(a0, b0, c, 0, 0, 0);
    c = __builtin_amdgcn_mfma_f32_16x16x32_f16(a1, b1, c, 0, 0, 0);
    acc[nt] = c;
  }

  const int rbase = row0 + m0 + lq * 4;
#pragma unroll
  for (int nt = 0; nt < 8; nt++) {
    const int cn = bn0 + nt * 16 + lm;  // combined col (branch wave-uniform)
    if (cn < COLS) {
#pragma unroll
      for (int r = 0; r < 4; r++)
        if (rbase + r < N)
          xl[(size_t)(rbase + r) * COLS + cn] = (_Float16)acc[nt][r];
    } else {
      const int cx = cn - COLS;
#pragma unroll
      for (int r = 0; r < 4; r++)
        if (rbase + r < N)
          xr[(size_t)(rbase + r) * COLS + cx] = (_Float16)acc[nt][r];
    }
  }
}

// ---------------------------------------------------------------------------
// CSR build (R11 config): single-pass deg count capturing per-edge rank.
__global__ __launch_bounds__(256) void count_kernel(const int* __restrict__ ei,
                                                    int E, int ET,
                                                    int* __restrict__ deg,
                                                    int* __restrict__ rank) {
  const int e = blockIdx.x * 256 + threadIdx.x;
  if (e >= ET) return;
  const int d = (e < E) ? ei[E + e] : (e - E);
  rank[e] = atomicAdd(deg + d, 1);  // rank = position within dst segment
}

// Phase 1: per-block (1024 elems) exclusive prefix into pre[], block totals.
__global__ __launch_bounds__(256) void scan_local_kernel(
    const int* __restrict__ deg, int* __restrict__ pre,
    int* __restrict__ bsums, int N) {
  const int t = threadIdx.x;
  const int i0 = blockIdx.x * 1024 + t * 4;
  int4 v;
  if (i0 + 3 < N) {
    v = *(const int4*)(deg + i0);
  } else {
    v.x = (i0 + 0 < N) ? deg[i0 + 0] : 0;
    v.y = (i0 + 1 < N) ? deg[i0 + 1] : 0;
    v.z = (i0 + 2 < N) ? deg[i0 + 2] : 0;
    v.w = (i0 + 3 < N) ? deg[i0 + 3] : 0;
  }
  const int s = v.x + v.y + v.z + v.w;
  const int lane = t & 63, wave = t >> 6;
  int x = s;
#pragma unroll
  for (int off = 1; off < 64; off <<= 1) {
    const int y = __shfl_up(x, off);
    if (lane >= off) x += y;
  }
  __shared__ int wsum[4];
  if (lane == 63) wsum[wave] = x;
  __syncthreads();
  int wbase = 0;
#pragma unroll
  for (int w = 0; w < 3; w++)
    if (w < wave) wbase += wsum[w];
  const int ex = wbase + (x - s);
  if (i0 + 3 < N) {
    int4 o;
    o.x = ex;
    o.y = ex + v.x;
    o.z = o.y + v.y;
    o.w = o.z + v.z;
    *(int4*)(pre + i0) = o;
  } else {
    int run = ex;
    if (i0 + 0 < N) pre[i0 + 0] = run;
    run += v.x;
    if (i0 + 1 < N) pre[i0 + 1] = run;
    run += v.y;
    if (i0 + 2 < N) pre[i0 + 2] = run;
    run += v.z;
    if (i0 + 3 < N) pre[i0 + 3] = run;
  }
  if (t == 255) bsums[blockIdx.x] = wbase + x;  // block total
}

// Histogram of degrees (64 bins) for the counting sort.
__global__ __launch_bounds__(256) void deg_hist_kernel(
    const int* __restrict__ deg, int* __restrict__ hist, int N) {
  __shared__ int lh[64];
  const int t = threadIdx.x;
  if (t < 64) lh[t] = 0;
  __syncthreads();
  const int i = blockIdx.x * 256 + t;
  if (i < N) atomicAdd(&lh[min(deg[i], 63)], 1);
  __syncthreads();
  if (t < 64 && lh[t] > 0) atomicAdd(hist + t, lh[t]);
}

// Fused small scans (2 blocks): block 0 = descending-exclusive hist scan
// (order base offsets); block 1 = exclusive scan of B (<=128) block sums.
__global__ __launch_bounds__(128) void scan2_kernel(int* __restrict__ hist,
                                                    int* __restrict__ bsums,
                                                    int B) {
  const int t = threadIdx.x;
  if (blockIdx.x == 0) {
    if (t < 64) {
      const int rv = hist[63 - t];  // reverse -> high degree first
      int x = rv;
#pragma unroll
      for (int off = 1; off < 64; off <<= 1) {
        const int y = __shfl_up(x, off);
        if (t >= off) x += y;
      }
      hist[63 - t] = x - rv;  // exclusive sum of higher-degree bins
    }
  } else {
    const int lane = t & 63, wave = t >> 6;
    const int v = (t < B) ? bsums[t] : 0;
    int x = v;
#pragma unroll
    for (int off = 1; off < 64; off <<= 1) {
      const int y = __shfl_up(x, off);
      if (lane >= off) x += y;
    }
    __shared__ int ws0;
    if (wave == 0 && lane == 63) ws0 = x;
    __syncthreads();
    const int base = wave ? ws0 : 0;
    if (t < B) bsums[t] = base + x - v;  // exclusive
  }
}

// Fused finalize: row_ofs += block base (scan phase 3), row_ofs[N]=ET, and
// counting-sort order fill (uses scanned hist as cursor). No cursor copy —
// fill uses rank[] (deterministic positions, no atomics).
__global__ __launch_bounds__(256) void finalize_kernel(
    int* __restrict__ row_ofs, const int* __restrict__ bsums,
    const int* __restrict__ deg, int* __restrict__ hist,
    int* __restrict__ order, int N, int ET) {
  __shared__ int lh[64];
  __shared__ int base[64];
  const int t = threadIdx.x;
  if (t < 64) lh[t] = 0;
  __syncthreads();
  const int i = blockIdx.x * 256 + t;
  if (i == 0) row_ofs[N] = ET;  // total statically known
  int b = 0, r = 0;
  if (i < N) {
    row_ofs[i] += bsums[i >> 10];
    b = min(deg[i], 63);
    r = atomicAdd(&lh[b], 1);
  }
  __syncthreads();
  if (t < 64 && lh[t] > 0) base[t] = atomicAdd(hist + t, lh[t]);
  __syncthreads();
  if (i < N) order[base[b] + r] = i;
}

// XCD-sliced CSR fill (R11 config): block (blockIdx&7) writes only dsts in
// its N/8 range, so each 64B csr_src line is dirtied within a single XCD's
// L2 and written back once. rank[] precomputed in count (no atomics here).
// XCD mapping is a locality heuristic only; correctness holds regardless.
__global__ __launch_bounds__(256) void fill_kernel(
    const int* __restrict__ ei, const int* __restrict__ rank,
    const int* __restrict__ row_ofs, int E, int ET, int nSlice,
    int* __restrict__ csr_src) {
  const int xcd = blockIdx.x & 7;
  const int bId = blockIdx.x >> 3;
  const int nB = gridDim.x >> 3;
  const int dlo = xcd * nSlice, dhi = dlo + nSlice;
  for (int e = bId * 256 + threadIdx.x; e < ET; e += nB * 256) {
    const int d = (e < E) ? ei[E + e] : (e - E);
    if (d < dlo || d >= dhi) continue;
    const int s = (e < E) ? ei[e] : d;
    csr_src[row_ofs[d] + rank[e]] = s;
  }
}

// ---------------------------------------------------------------------------
// packed-fp16 score of one 8-channel chunk: sc += dot(leaky(x+xr), att)
__device__ __forceinline__ float score8(const H8 xv, const h2* __restrict__ xrh,
                                        const h2* __restrict__ ath, int q0,
                                        float sc) {
  const h2 slope = {(_Float16)NSLOPE, (_Float16)NSLOPE};
#pragma unroll
  for (int q = 0; q < 4; q++) {
    h2 v = xv.h[q] + xrh[q0 + q];
    h2 lk = __builtin_elementwise_max(v, v * slope);  // slope<1 => exact leaky
    sc = __builtin_amdgcn_fdot2(lk, ath[q0 + q], sc, false);
  }
  return sc;
}

// Fused per-(node,head) no-max-softmax aggregation, SPLIT-way edge partition
// (SPLIT lanes per (node,head), merged by log2(SPLIT) shfl_xor rounds),
// nodes processed in degree-sorted order (order[]). Softmax sum is
// order-independent so any neighbor order in csr_src is fine.
// MODE 0 (SPLIT=2): out fp16 [n*H*C + h*C + c] = elu(agg + bias)
// MODE 1: out fp32 [n*C + c] = mean_h(agg) + bias (butterfly over h lanes)
template <int C, int MODE, int SPLIT>
__global__ __launch_bounds__(256) void node_agg_kernel(
    const _Float16* __restrict__ xl, const _Float16* __restrict__ xr,
    const float* __restrict__ att, const float* __restrict__ bias,
    const int* __restrict__ row_ofs, const int* __restrict__ csr_src,
    const int* __restrict__ order, void* __restrict__ out, int N) {
  const int t = blockIdx.x * 256 + threadIdx.x;
  if (t >= N * HEADS * SPLIT) return;
  const int n = order[t / (HEADS * SPLIT)];
  const int h = t & 3;
  const int p = (t >> 2) & (SPLIT - 1);
  constexpr int Q = C / 8;  // half8 chunks per row
  h2 xrh[C / 2], ath[C / 2];
  {
    const h2* xrp = (const h2*)(xr + ((size_t)n * HEADS + h) * C);
    const float4* atp = (const float4*)(att + h * C);
#pragma unroll
    for (int q = 0; q < C / 2; q++) xrh[q] = xrp[q];
#pragma unroll
    for (int q = 0; q < C / 4; q++) {
      const float4 av = atp[q];
      ath[2 * q + 0] = h2{(_Float16)av.x, (_Float16)av.y};
      ath[2 * q + 1] = h2{(_Float16)av.z, (_Float16)av.w};
    }
  }
  float acc[C];
#pragma unroll
  for (int c = 0; c < C; c++) acc[c] = 0.f;
  float l = 0.f;
  const int jb = row_ofs[n], je = row_ofs[n + 1];
  int j = jb + p;
  // dual-edge: 2 gathers in flight per lane
  for (; j + SPLIT < je; j += 2 * SPLIT) {
    const int s0 = csr_src[j], s1 = csr_src[j + SPLIT];
    const half8* xp0 = (const half8*)(xl + ((size_t)s0 * HEADS + h) * C);
    const half8* xp1 = (const half8*)(xl + ((size_t)s1 * HEADS + h) * C);
    H8 a[Q], b[Q];
#pragma unroll
    for (int q = 0; q < Q; q++) {
      a[q].v = xp0[q];
      b[q].v = xp1[q];
    }
    float sc0 = 0.f, sc1 = 0.f;
#pragma unroll
    for (int q = 0; q < Q; q++) {
      sc0 = score8(a[q], xrh, ath, 4 * q, sc0);
      sc1 = score8(b[q], xrh, ath, 4 * q, sc1);
    }
    const float e0 = __expf(sc0);
    const float e1 = __expf(sc1);
    l += e0 + e1;
#pragma unroll
    for (int q = 0; q < Q; q++)
#pragma unroll
      for (int k = 0; k < 4; k++) {
        const int c = 8 * q + 2 * k;
        acc[c + 0] = fmaf(e0, (float)a[q].h[k][0], acc[c + 0]);
        acc[c + 1] = fmaf(e0, (float)a[q].h[k][1], acc[c + 1]);
        acc[c + 0] = fmaf(e1, (float)b[q].h[k][0], acc[c + 0]);
        acc[c + 1] = fmaf(e1, (float)b[q].h[k][1], acc[c + 1]);
      }
  }
  for (; j < je; j += SPLIT) {
    const int s = csr_src[j];
    const half8* xp = (const half8*)(xl + ((size_t)s * HEADS + h) * C);
    H8 a[Q];
#pragma unroll
    for (int q = 0; q < Q; q++) a[q].v = xp[q];
    float sc = 0.f;
#pragma unroll
    for (int q = 0; q < Q; q++) sc = score8(a[q], xrh, ath, 4 * q, sc);
    const float e = __expf(sc);
    l += e;
#pragma unroll
    for (int q = 0; q < Q; q++)
#pragma unroll
      for (int k = 0; k < 4; k++) {
        const int c = 8 * q + 2 * k;
        acc[c + 0] = fmaf(e, (float)a[q].h[k][0], acc[c + 0]);
        acc[c + 1] = fmaf(e, (float)a[q].h[k][1], acc[c + 1]);
      }
  }

  // merge split partners (lanes t^4, t^8, ...): plain adds (no max state).
#pragma unroll
  for (int m = 4; m < 4 * SPLIT; m <<= 1) {
    l += __shfl_xor(l, m);
#pragma unroll
    for (int c = 0; c < C; c++) acc[c] += __shfl_xor(acc[c], m);
  }
  const float inv_ = 1.f / l;

  if (MODE == 0) {
    _Float16* o = (_Float16*)out;
    const int c0 = p * (C / 2);  // this lane's half of the channels (C=16: 8)
    half8 hv;
#pragma unroll
    for (int c = 0; c < C / 2; c++) {
      const float v = fmaf(acc[c0 + c], inv_, bias[h * C + c0 + c]);
      hv[c] = (_Float16)(v > 0.f ? v : (__expf(v) - 1.f));
    }
    *(half8*)(o + ((size_t)n * HEADS + h) * C + c0) = hv;
  } else {
    // head-mean butterfly over h bits (lanes ^1, ^2); all p copies compute
    // the identical mean. Whole lane-groups alive (N*4*SPLIT % group == 0).
    float* o = (float*)out;
#pragma unroll
    for (int c = 0; c < C; c++) {
      float v = acc[c] * inv_;
      v += __shfl_xor(v, 1);
      v += __shfl_xor(v, 2);
      acc[c] = v * 0.25f;
    }
    const int il = t & (4 * SPLIT - 1);  // lane-in-node
    constexpr int CPL = C / (4 * SPLIT); // channels per lane
    const int c0 = il * CPL;
    if constexpr (CPL == 4) {
      float4 ob;
      ob.x = acc[c0 + 0] + bias[c0 + 0];
      ob.y = acc[c0 + 1] + bias[c0 + 1];
      ob.z = acc[c0 + 2] + bias[c0 + 2];
      ob.w = acc[c0 + 3] + bias[c0 + 3];
      *(float4*)(o + (size_t)n * C + c0) = ob;
    } else {
      float2 ob;
      ob.x = acc[c0 + 0] + bias[c0 + 0];
      ob.y = acc[c0 + 1] + bias[c0 + 1];
      *(float2*)(o + (size_t)n * C + c0) = ob;
    }
  }
}

// ---------------------------------------------------------------------------
extern "C" void kernel_launch(void* const* d_in, const int* in_sizes, int n_in,
                              void* d_out, int out_size, void* d_ws,
                              size_t ws_size, hipStream_t stream) {
  const float* x = (const float*)d_in[0];
  const int* ei = (const int*)d_in[1];
  const float* W1l = (const float*)d_in[2];
  const float* W1r = (const float*)d_in[3];
  const float* a1 = (const float*)d_in[4];
  const float* b1 = (const float*)d_in[5];
  const float* W2l = (const float*)d_in[6];
  const float* W2r = (const float*)d_in[7];
  const float* a2 = (const float*)d_in[8];
  const float* b2 = (const float*)d_in[9];
  const float* W3l = (const float*)d_in[10];
  const float* W3r = (const float*)d_in[11];
  const float* a3 = (const float*)d_in[12];
  const float* b3 = (const float*)d_in[13];

  const int N = in_sizes[0] / 64;
  const int E = in_sizes[1] / 2;
  const int ET = E + N;

  char* ws = (char*)d_ws;
  const size_t szXl = (size_t)N * 128 * sizeof(_Float16);  // 25.6 MB
  const size_t szXr = (size_t)N * 128 * sizeof(_Float16);  // 25.6 MB
  const size_t szH = (size_t)N * 64 * sizeof(_Float16);    // 12.8 MB
  _Float16* xl = (_Float16*)(ws);
  _Float16* xr = (_Float16*)(ws + szXl);
  _Float16* h1 = (_Float16*)(ws + szXl + szXr);
  _Float16* h2b = (_Float16*)(ws + szXl + szXr + szH);
  char* p = ws + szXl + szXr + 2 * szH;
  int* deg = (int*)p;                                  p += (size_t)N * 4;
  int* row_ofs = (int*)p;                              p += (size_t)(N + 1) * 4;
  int* bsums = (int*)p;                                p += 128 * 4;
  int* hist = (int*)p;                                 p += 64 * 4;
  int* order = (int*)p;                                p += (size_t)N * 4;
  p = (char*)(((uintptr_t)p + 15) & ~(uintptr_t)15);
  int* rank = (int*)p;                                 p += (size_t)ET * 4;
  p = (char*)(((uintptr_t)p + 15) & ~(uintptr_t)15);
  int* csr_src = (int*)p;                              p += (size_t)ET * 4;
  p = (char*)(((uintptr_t)p + 15) & ~(uintptr_t)15);
  _Float16* wt1 = (_Float16*)p;                        p += 8192 * 2;
  _Float16* wt2 = (_Float16*)p;                        p += 8192 * 2;
  _Float16* wt3 = (_Float16*)p;                        p += 16384 * 2;

  const int edgeBlocks = (ET + 255) / 256;
  const int nodeBlocks = (N + 255) / 256;
  const int nh2Blocks = (N * HEADS * 2 + 255) / 256;
  const int nh4Blocks = (N * HEADS * 4 + 255) / 256;
  const int rowBlocks = (N + 63) / 64;
  const int scanBlocks = (N + 1023) / 1024;  // 98 <= 128
  const int nSlice = (N + 7) / 8;
  const dim3 g128(rowBlocks, 1), g256(rowBlocks, 2);

  // ---- preamble: W^T + zero, CSR build, degree sort ----
  wt_build_zero_kernel<<<512, 256, 0, stream>>>(W1l, W1r, W2l, W2r, W3l, W3r,
                                                wt1, wt2, wt3, deg, hist, N);
  count_kernel<<<edgeBlocks, 256, 0, stream>>>(ei, E, ET, deg, rank);
  deg_hist_kernel<<<nodeBlocks, 256, 0, stream>>>(deg, hist, N);
  scan_local_kernel<<<scanBlocks, 256, 0, stream>>>(deg, row_ofs, bsums, N);
  scan2_kernel<<<2, 128, 0, stream>>>(hist, bsums, scanBlocks);
  finalize_kernel<<<nodeBlocks, 256, 0, stream>>>(row_ofs, bsums, deg, hist,
                                                  order, N, ET);
  fill_kernel<<<8 * 96, 256, 0, stream>>>(ei, rank, row_ofs, E, ET, nSlice,
                                          csr_src);

  // ---- Layer 1: 64 -> 4x16, concat, ELU ----
  gemm_mfma_kernel<128, true><<<g128, 256, 0, stream>>>(x, wt1, xl, xr, N);
  node_agg_kernel<16, 0, 2><<<nh2Blocks, 256, 0, stream>>>(
      xl, xr, a1, b1, row_ofs, csr_src, order, h1, N);
  // ---- Layer 2: 64 -> 4x16, concat, ELU ----
  gemm_mfma_kernel<128, false><<<g128, 256, 0, stream>>>(h1, wt2, xl, xr, N);
  node_agg_kernel<16, 0, 2><<<nh2Blocks, 256, 0, stream>>>(
      xl, xr, a2, b2, row_ofs, csr_src, order, h2b, N);
  // ---- Layer 3: 64 -> 4x32, mean over heads; split-4 (16 lanes/node) ----
  gemm_mfma_kernel<256, false><<<g256, 256, 0, stream>>>(h2b, wt3, xl, xr, N);
  node_agg_kernel<32, 1, 4><<<nh4Blocks, 256, 0, stream>>>(
      xl, xr, a3, b3, row_ofs, csr_src, order, d_out, N);
}

// Round 15
// 323.112 us; speedup vs baseline: 1.0413x; 1.0413x over previous
//
#include <hip/hip_runtime.h>
#include <math.h>

// GATv2 3-layer forward, MI355X.
// R14: best-of-measured recombination. R13's split-4 layer-3 agg REGRESSED
// (55->70us: with ~2.3 edges/lane the 16x-replicated xr/att staging + extra
// merge round outweigh the shorter chain — confirms agg3 sits at the ~2.5 TB/s
// random-gather wall at split-2). Revert L3 agg to SPLIT=2; keep R13 preamble
// (R11-config rank-capture count + XCD-sliced rank fill, fused small kernels).
// R10 degree-sort + fp16 staging, R9 MFMA GEMM, R7 no-max softmax agg kept.
// N=100000, E=800000 (+N self loops), Fin=64, H=4, C=16/16/32.

#define HEADS 4
#define NSLOPE 0.2f

typedef __attribute__((ext_vector_type(8))) _Float16 half8;
typedef __attribute__((ext_vector_type(2))) _Float16 h2;
typedef __attribute__((ext_vector_type(4))) float f32x4;

union H8 {
  half8 v;
  h2 h[4];
};

// ---------------------------------------------------------------------------
// One-time: build fp16 W^T for all 3 layers (wt[c*64+k] = W[k][c], combined
// [Wl | Wr] cols) + zero deg/hist (replaces 2 memsets).
__global__ __launch_bounds__(256) void wt_build_zero_kernel(
    const float* __restrict__ W1l, const float* __restrict__ W1r,
    const float* __restrict__ W2l, const float* __restrict__ W2r,
    const float* __restrict__ W3l, const float* __restrict__ W3r,
    _Float16* __restrict__ wt1, _Float16* __restrict__ wt2,
    _Float16* __restrict__ wt3, int* __restrict__ deg, int* __restrict__ hist,
    int N) {
  const int tid = blockIdx.x * 256 + threadIdx.x;
  for (int i = tid; i < N; i += gridDim.x * 256) deg[i] = 0;
  if (tid < 64) hist[tid] = 0;
  int i = tid;
  const float *Wl, *Wr;
  _Float16* wt;
  int COLS;
  if (i < 8192) {
    Wl = W1l; Wr = W1r; wt = wt1; COLS = 64;
  } else if (i < 16384) {
    i -= 8192; Wl = W2l; Wr = W2r; wt = wt2; COLS = 64;
  } else if (i < 32768) {
    i -= 16384; Wl = W3l; Wr = W3r; wt = wt3; COLS = 128;
  } else {
    return;
  }
  const int c = i >> 6, k = i & 63;
  const float v = (c < COLS) ? Wl[k * COLS + c] : Wr[k * COLS + (c - COLS)];
  wt[i] = (_Float16)v;
}

// ---------------------------------------------------------------------------
// MFMA GEMM: [xl | xr] (both fp16) = in @ [Wl | Wr], K=64, via
// mfma_f32_16x16x32_f16. Block: 64 rows x 128 combined cols, 4 waves.
// FP32IN: layer-1 input is fp32; layers 2-3 input (h) is fp16.
// A-frag: A[m=lane&15][k=quad*8+j]; B-frag: B[k=quad*8+j][n=lane&15];
// C/D: col=lane&15, row=quad*4+reg (m89-verified mapping).
template <int TOTAL, bool FP32IN>
__global__ __launch_bounds__(256) void gemm_mfma_kernel(
    const void* __restrict__ in_v, const _Float16* __restrict__ wt,
    _Float16* __restrict__ xl, _Float16* __restrict__ xr, int N) {
  constexpr int COLS = TOTAL / 2;
  __shared__ _Float16 xsh[64][72];   // A tile [m][k]
  __shared__ _Float16 bsh[128][72];  // B tile [n][k] (wt slice)
  const int row0 = blockIdx.x * 64;
  const int bn0 = blockIdx.y * 128;
  const int t = threadIdx.x;

  // stage A: thread owns row t&63, k-range (t>>6)*16..+15
  {
    const int r = t & 63, kq = t >> 6;
    const int row = row0 + r;
    half8 h0, h1;
    if (row < N) {
      if constexpr (FP32IN) {
        const float* inf = (const float*)in_v;
        const float4* src = (const float4*)(inf + (size_t)row * 64 + kq * 16);
        const float4 q0 = src[0], q1 = src[1], q2 = src[2], q3 = src[3];
        h0[0] = (_Float16)q0.x; h0[1] = (_Float16)q0.y;
        h0[2] = (_Float16)q0.z; h0[3] = (_Float16)q0.w;
        h0[4] = (_Float16)q1.x; h0[5] = (_Float16)q1.y;
        h0[6] = (_Float16)q1.z; h0[7] = (_Float16)q1.w;
        h1[0] = (_Float16)q2.x; h1[1] = (_Float16)q2.y;
        h1[2] = (_Float16)q2.z; h1[3] = (_Float16)q2.w;
        h1[4] = (_Float16)q3.x; h1[5] = (_Float16)q3.y;
        h1[6] = (_Float16)q3.z; h1[7] = (_Float16)q3.w;
      } else {
        const _Float16* inh = (const _Float16*)in_v;
        const half8* src = (const half8*)(inh + (size_t)row * 64 + kq * 16);
        h0 = src[0];
        h1 = src[1];
      }
    } else {
#pragma unroll
      for (int j = 0; j < 8; j++) {
        h0[j] = (_Float16)0.f;
        h1[j] = (_Float16)0.f;
      }
    }
    *(half8*)&xsh[r][kq * 16] = h0;
    *(half8*)&xsh[r][kq * 16 + 8] = h1;
  }
  // stage B: 128 wt rows x 64 halves; thread t copies 32 halves of row t>>1
  {
    const int rr = t >> 1, hh = t & 1;
    const half8* src = (const half8*)(wt + ((size_t)(bn0 + rr) << 6) + hh * 32);
    const half8 b0 = src[0], b1 = src[1], b2 = src[2], b3 = src[3];
    half8* dst = (half8*)&bsh[rr][hh * 32];
    dst[0] = b0; dst[1] = b1; dst[2] = b2; dst[3] = b3;
  }
  __syncthreads();

  const int lane = t & 63, w = t >> 6;
  const int lm = lane & 15, lq = lane >> 4;
  const int m0 = w * 16;
  const half8 a0 = *(const half8*)&xsh[m0 + lm][lq * 8];
  const half8 a1 = *(const half8*)&xsh[m0 + lm][32 + lq * 8];
  f32x4 acc[8];
#pragma unroll
  for (int nt = 0; nt < 8; nt++) {
    const half8 b0 = *(const half8*)&bsh[nt * 16 + lm][lq * 8];
    const half8 b1 = *(const half8*)&bsh[nt * 16 + lm][32 + lq * 8];
    f32x4 c = {0.f, 0.f, 0.f, 0.f};
    c = __builtin_amdgcn_mfma_f32_16x16x32_f16(a0, b0, c, 0, 0, 0);
    c = __builtin_amdgcn_mfma_f32_16x16x32_f16(a1, b1, c, 0, 0, 0);
    acc[nt] = c;
  }

  const int rbase = row0 + m0 + lq * 4;
#pragma unroll
  for (int nt = 0; nt < 8; nt++) {
    const int cn = bn0 + nt * 16 + lm;  // combined col (branch wave-uniform)
    if (cn < COLS) {
#pragma unroll
      for (int r = 0; r < 4; r++)
        if (rbase + r < N)
          xl[(size_t)(rbase + r) * COLS + cn] = (_Float16)acc[nt][r];
    } else {
      const int cx = cn - COLS;
#pragma unroll
      for (int r = 0; r < 4; r++)
        if (rbase + r < N)
          xr[(size_t)(rbase + r) * COLS + cx] = (_Float16)acc[nt][r];
    }
  }
}

// ---------------------------------------------------------------------------
// CSR build (R11 config): single-pass deg count capturing per-edge rank.
__global__ __launch_bounds__(256) void count_kernel(const int* __restrict__ ei,
                                                    int E, int ET,
                                                    int* __restrict__ deg,
                                                    int* __restrict__ rank) {
  const int e = blockIdx.x * 256 + threadIdx.x;
  if (e >= ET) return;
  const int d = (e < E) ? ei[E + e] : (e - E);
  rank[e] = atomicAdd(deg + d, 1);  // rank = position within dst segment
}

// Phase 1: per-block (1024 elems) exclusive prefix into pre[], block totals.
__global__ __launch_bounds__(256) void scan_local_kernel(
    const int* __restrict__ deg, int* __restrict__ pre,
    int* __restrict__ bsums, int N) {
  const int t = threadIdx.x;
  const int i0 = blockIdx.x * 1024 + t * 4;
  int4 v;
  if (i0 + 3 < N) {
    v = *(const int4*)(deg + i0);
  } else {
    v.x = (i0 + 0 < N) ? deg[i0 + 0] : 0;
    v.y = (i0 + 1 < N) ? deg[i0 + 1] : 0;
    v.z = (i0 + 2 < N) ? deg[i0 + 2] : 0;
    v.w = (i0 + 3 < N) ? deg[i0 + 3] : 0;
  }
  const int s = v.x + v.y + v.z + v.w;
  const int lane = t & 63, wave = t >> 6;
  int x = s;
#pragma unroll
  for (int off = 1; off < 64; off <<= 1) {
    const int y = __shfl_up(x, off);
    if (lane >= off) x += y;
  }
  __shared__ int wsum[4];
  if (lane == 63) wsum[wave] = x;
  __syncthreads();
  int wbase = 0;
#pragma unroll
  for (int w = 0; w < 3; w++)
    if (w < wave) wbase += wsum[w];
  const int ex = wbase + (x - s);
  if (i0 + 3 < N) {
    int4 o;
    o.x = ex;
    o.y = ex + v.x;
    o.z = o.y + v.y;
    o.w = o.z + v.z;
    *(int4*)(pre + i0) = o;
  } else {
    int run = ex;
    if (i0 + 0 < N) pre[i0 + 0] = run;
    run += v.x;
    if (i0 + 1 < N) pre[i0 + 1] = run;
    run += v.y;
    if (i0 + 2 < N) pre[i0 + 2] = run;
    run += v.z;
    if (i0 + 3 < N) pre[i0 + 3] = run;
  }
  if (t == 255) bsums[blockIdx.x] = wbase + x;  // block total
}

// Histogram of degrees (64 bins) for the counting sort.
__global__ __launch_bounds__(256) void deg_hist_kernel(
    const int* __restrict__ deg, int* __restrict__ hist, int N) {
  __shared__ int lh[64];
  const int t = threadIdx.x;
  if (t < 64) lh[t] = 0;
  __syncthreads();
  const int i = blockIdx.x * 256 + t;
  if (i < N) atomicAdd(&lh[min(deg[i], 63)], 1);
  __syncthreads();
  if (t < 64 && lh[t] > 0) atomicAdd(hist + t, lh[t]);
}

// Fused small scans (2 blocks): block 0 = descending-exclusive hist scan
// (order base offsets); block 1 = exclusive scan of B (<=128) block sums.
__global__ __launch_bounds__(128) void scan2_kernel(int* __restrict__ hist,
                                                    int* __restrict__ bsums,
                                                    int B) {
  const int t = threadIdx.x;
  if (blockIdx.x == 0) {
    if (t < 64) {
      const int rv = hist[63 - t];  // reverse -> high degree first
      int x = rv;
#pragma unroll
      for (int off = 1; off < 64; off <<= 1) {
        const int y = __shfl_up(x, off);
        if (t >= off) x += y;
      }
      hist[63 - t] = x - rv;  // exclusive sum of higher-degree bins
    }
  } else {
    const int lane = t & 63, wave = t >> 6;
    const int v = (t < B) ? bsums[t] : 0;
    int x = v;
#pragma unroll
    for (int off = 1; off < 64; off <<= 1) {
      const int y = __shfl_up(x, off);
      if (lane >= off) x += y;
    }
    __shared__ int ws0;
    if (wave == 0 && lane == 63) ws0 = x;
    __syncthreads();
    const int base = wave ? ws0 : 0;
    if (t < B) bsums[t] = base + x - v;  // exclusive
  }
}

// Fused finalize: row_ofs += block base (scan phase 3), row_ofs[N]=ET, and
// counting-sort order fill (uses scanned hist as cursor). No cursor copy —
// fill uses rank[] (deterministic positions, no atomics).
__global__ __launch_bounds__(256) void finalize_kernel(
    int* __restrict__ row_ofs, const int* __restrict__ bsums,
    const int* __restrict__ deg, int* __restrict__ hist,
    int* __restrict__ order, int N, int ET) {
  __shared__ int lh[64];
  __shared__ int base[64];
  const int t = threadIdx.x;
  if (t < 64) lh[t] = 0;
  __syncthreads();
  const int i = blockIdx.x * 256 + t;
  if (i == 0) row_ofs[N] = ET;  // total statically known
  int b = 0, r = 0;
  if (i < N) {
    row_ofs[i] += bsums[i >> 10];
    b = min(deg[i], 63);
    r = atomicAdd(&lh[b], 1);
  }
  __syncthreads();
  if (t < 64 && lh[t] > 0) base[t] = atomicAdd(hist + t, lh[t]);
  __syncthreads();
  if (i < N) order[base[b] + r] = i;
}

// XCD-sliced CSR fill (R11 config): block (blockIdx&7) writes only dsts in
// its N/8 range, so each 64B csr_src line is dirtied within a single XCD's
// L2 and written back once. rank[] precomputed in count (no atomics here).
// XCD mapping is a locality heuristic only; correctness holds regardless.
__global__ __launch_bounds__(256) void fill_kernel(
    const int* __restrict__ ei, const int* __restrict__ rank,
    const int* __restrict__ row_ofs, int E, int ET, int nSlice,
    int* __restrict__ csr_src) {
  const int xcd = blockIdx.x & 7;
  const int bId = blockIdx.x >> 3;
  const int nB = gridDim.x >> 3;
  const int dlo = xcd * nSlice, dhi = dlo + nSlice;
  for (int e = bId * 256 + threadIdx.x; e < ET; e += nB * 256) {
    const int d = (e < E) ? ei[E + e] : (e - E);
    if (d < dlo || d >= dhi) continue;
    const int s = (e < E) ? ei[e] : d;
    csr_src[row_ofs[d] + rank[e]] = s;
  }
}

// ---------------------------------------------------------------------------
// packed-fp16 score of one 8-channel chunk: sc += dot(leaky(x+xr), att)
__device__ __forceinline__ float score8(const H8 xv, const h2* __restrict__ xrh,
                                        const h2* __restrict__ ath, int q0,
                                        float sc) {
  const h2 slope = {(_Float16)NSLOPE, (_Float16)NSLOPE};
#pragma unroll
  for (int q = 0; q < 4; q++) {
    h2 v = xv.h[q] + xrh[q0 + q];
    h2 lk = __builtin_elementwise_max(v, v * slope);  // slope<1 => exact leaky
    sc = __builtin_amdgcn_fdot2(lk, ath[q0 + q], sc, false);
  }
  return sc;
}

// Fused per-(node,head) no-max-softmax aggregation, split-2 over edges,
// nodes processed in degree-sorted order (order[]). Softmax sum is
// order-independent so any neighbor order in csr_src is fine.
// MODE 0: out fp16 [n*H*C + h*C + c] = elu(agg + bias)
// MODE 1: out fp32 [n*C + c] = mean_h(agg) + bias (8-lane butterfly)
template <int C, int MODE>
__global__ __launch_bounds__(256) void node_agg_kernel(
    const _Float16* __restrict__ xl, const _Float16* __restrict__ xr,
    const float* __restrict__ att, const float* __restrict__ bias,
    const int* __restrict__ row_ofs, const int* __restrict__ csr_src,
    const int* __restrict__ order, void* __restrict__ out, int N) {
  const int t = blockIdx.x * 256 + threadIdx.x;
  if (t >= N * HEADS * 2) return;
  const int n = order[t >> 3];
  const int h = t & 3;
  const int p = (t >> 2) & 1;
  constexpr int Q = C / 8;  // half8 chunks per row
  h2 xrh[C / 2], ath[C / 2];
  {
    const h2* xrp = (const h2*)(xr + ((size_t)n * HEADS + h) * C);
    const float4* atp = (const float4*)(att + h * C);
#pragma unroll
    for (int q = 0; q < C / 2; q++) xrh[q] = xrp[q];
#pragma unroll
    for (int q = 0; q < C / 4; q++) {
      const float4 av = atp[q];
      ath[2 * q + 0] = h2{(_Float16)av.x, (_Float16)av.y};
      ath[2 * q + 1] = h2{(_Float16)av.z, (_Float16)av.w};
    }
  }
  float acc[C];
#pragma unroll
  for (int c = 0; c < C; c++) acc[c] = 0.f;
  float l = 0.f;
  const int jb = row_ofs[n], je = row_ofs[n + 1];
  int j = jb + p;
  // dual-edge: 2 gathers in flight per lane
  for (; j + 2 < je; j += 4) {
    const int s0 = csr_src[j], s1 = csr_src[j + 2];
    const half8* xp0 = (const half8*)(xl + ((size_t)s0 * HEADS + h) * C);
    const half8* xp1 = (const half8*)(xl + ((size_t)s1 * HEADS + h) * C);
    H8 a[Q], b[Q];
#pragma unroll
    for (int q = 0; q < Q; q++) {
      a[q].v = xp0[q];
      b[q].v = xp1[q];
    }
    float sc0 = 0.f, sc1 = 0.f;
#pragma unroll
    for (int q = 0; q < Q; q++) {
      sc0 = score8(a[q], xrh, ath, 4 * q, sc0);
      sc1 = score8(b[q], xrh, ath, 4 * q, sc1);
    }
    const float e0 = __expf(sc0);
    const float e1 = __expf(sc1);
    l += e0 + e1;
#pragma unroll
    for (int q = 0; q < Q; q++)
#pragma unroll
      for (int k = 0; k < 4; k++) {
        const int c = 8 * q + 2 * k;
        acc[c + 0] = fmaf(e0, (float)a[q].h[k][0], acc[c + 0]);
        acc[c + 1] = fmaf(e0, (float)a[q].h[k][1], acc[c + 1]);
        acc[c + 0] = fmaf(e1, (float)b[q].h[k][0], acc[c + 0]);
        acc[c + 1] = fmaf(e1, (float)b[q].h[k][1], acc[c + 1]);
      }
  }
  for (; j < je; j += 2) {
    const int s = csr_src[j];
    const half8* xp = (const half8*)(xl + ((size_t)s * HEADS + h) * C);
    H8 a[Q];
#pragma unroll
    for (int q = 0; q < Q; q++) a[q].v = xp[q];
    float sc = 0.f;
#pragma unroll
    for (int q = 0; q < Q; q++) sc = score8(a[q], xrh, ath, 4 * q, sc);
    const float e = __expf(sc);
    l += e;
#pragma unroll
    for (int q = 0; q < Q; q++)
#pragma unroll
      for (int k = 0; k < 4; k++) {
        const int c = 8 * q + 2 * k;
        acc[c + 0] = fmaf(e, (float)a[q].h[k][0], acc[c + 0]);
        acc[c + 1] = fmaf(e, (float)a[q].h[k][1], acc[c + 1]);
      }
  }

  // merge split pair (partner lane = t ^ 4): plain adds (no max state).
  l += __shfl_xor(l, 4);
#pragma unroll
  for (int c = 0; c < C; c++) acc[c] += __shfl_xor(acc[c], 4);
  const float inv_ = 1.f / l;

  if (MODE == 0) {
    _Float16* o = (_Float16*)out;
    const int c0 = p * (C / 2);  // this lane's half of the channels (C=16: 8)
    half8 hv;
#pragma unroll
    for (int c = 0; c < C / 2; c++) {
      const float v = fmaf(acc[c0 + c], inv_, bias[h * C + c0 + c]);
      hv[c] = (_Float16)(v > 0.f ? v : (__expf(v) - 1.f));
    }
    *(half8*)(o + ((size_t)n * HEADS + h) * C + c0) = hv;
  } else {
    // head-mean butterfly over h bits (lanes ^1, ^2); both p halves compute
    // the identical mean. Whole 8-lane groups are alive (N*8 % 8 == 0).
    float* o = (float*)out;
#pragma unroll
    for (int c = 0; c < C; c++) {
      float v = acc[c] * inv_;
      v += __shfl_xor(v, 1);
      v += __shfl_xor(v, 2);
      acc[c] = v * 0.25f;
    }
    const int il = t & 7;         // lane-in-node
    const int c0 = il * (C / 8);  // C=32: 4 channels per lane
    float4 ob;
    ob.x = acc[c0 + 0] + bias[c0 + 0];
    ob.y = acc[c0 + 1] + bias[c0 + 1];
    ob.z = acc[c0 + 2] + bias[c0 + 2];
    ob.w = acc[c0 + 3] + bias[c0 + 3];
    *(float4*)(o + (size_t)n * C + c0) = ob;
  }
}

// ---------------------------------------------------------------------------
extern "C" void kernel_launch(void* const* d_in, const int* in_sizes, int n_in,
                              void* d_out, int out_size, void* d_ws,
                              size_t ws_size, hipStream_t stream) {
  const float* x = (const float*)d_in[0];
  const int* ei = (const int*)d_in[1];
  const float* W1l = (const float*)d_in[2];
  const float* W1r = (const float*)d_in[3];
  const float* a1 = (const float*)d_in[4];
  const float* b1 = (const float*)d_in[5];
  const float* W2l = (const float*)d_in[6];
  const float* W2r = (const float*)d_in[7];
  const float* a2 = (const float*)d_in[8];
  const float* b2 = (const float*)d_in[9];
  const float* W3l = (const float*)d_in[10];
  const float* W3r = (const float*)d_in[11];
  const float* a3 = (const float*)d_in[12];
  const float* b3 = (const float*)d_in[13];

  const int N = in_sizes[0] / 64;
  const int E = in_sizes[1] / 2;
  const int ET = E + N;

  char* ws = (char*)d_ws;
  const size_t szXl = (size_t)N * 128 * sizeof(_Float16);  // 25.6 MB
  const size_t szXr = (size_t)N * 128 * sizeof(_Float16);  // 25.6 MB
  const size_t szH = (size_t)N * 64 * sizeof(_Float16);    // 12.8 MB
  _Float16* xl = (_Float16*)(ws);
  _Float16* xr = (_Float16*)(ws + szXl);
  _Float16* h1 = (_Float16*)(ws + szXl + szXr);
  _Float16* h2b = (_Float16*)(ws + szXl + szXr + szH);
  char* p = ws + szXl + szXr + 2 * szH;
  int* deg = (int*)p;                                  p += (size_t)N * 4;
  int* row_ofs = (int*)p;                              p += (size_t)(N + 1) * 4;
  int* bsums = (int*)p;                                p += 128 * 4;
  int* hist = (int*)p;                                 p += 64 * 4;
  int* order = (int*)p;                                p += (size_t)N * 4;
  p = (char*)(((uintptr_t)p + 15) & ~(uintptr_t)15);
  int* rank = (int*)p;                                 p += (size_t)ET * 4;
  p = (char*)(((uintptr_t)p + 15) & ~(uintptr_t)15);
  int* csr_src = (int*)p;                              p += (size_t)ET * 4;
  p = (char*)(((uintptr_t)p + 15) & ~(uintptr_t)15);
  _Float16* wt1 = (_Float16*)p;                        p += 8192 * 2;
  _Float16* wt2 = (_Float16*)p;                        p += 8192 * 2;
  _Float16* wt3 = (_Float16*)p;                        p += 16384 * 2;

  const int edgeBlocks = (ET + 255) / 256;
  const int nodeBlocks = (N + 255) / 256;
  const int nh2Blocks = (N * HEADS * 2 + 255) / 256;
  const int rowBlocks = (N + 63) / 64;
  const int scanBlocks = (N + 1023) / 1024;  // 98 <= 128
  const int nSlice = (N + 7) / 8;
  const dim3 g128(rowBlocks, 1), g256(rowBlocks, 2);

  // ---- preamble: W^T + zero, CSR build, degree sort ----
  wt_build_zero_kernel<<<512, 256, 0, stream>>>(W1l, W1r, W2l, W2r, W3l, W3r,
                                                wt1, wt2, wt3, deg, hist, N);
  count_kernel<<<edgeBlocks, 256, 0, stream>>>(ei, E, ET, deg, rank);
  deg_hist_kernel<<<nodeBlocks, 256, 0, stream>>>(deg, hist, N);
  scan_local_kernel<<<scanBlocks, 256, 0, stream>>>(deg, row_ofs, bsums, N);
  scan2_kernel<<<2, 128, 0, stream>>>(hist, bsums, scanBlocks);
  finalize_kernel<<<nodeBlocks, 256, 0, stream>>>(row_ofs, bsums, deg, hist,
                                                  order, N, ET);
  fill_kernel<<<8 * 96, 256, 0, stream>>>(ei, rank, row_ofs, E, ET, nSlice,
                                          csr_src);

  // ---- Layer 1: 64 -> 4x16, concat, ELU ----
  gemm_mfma_kernel<128, true><<<g128, 256, 0, stream>>>(x, wt1, xl, xr, N);
  node_agg_kernel<16, 0><<<nh2Blocks, 256, 0, stream>>>(
      xl, xr, a1, b1, row_ofs, csr_src, order, h1, N);
  // ---- Layer 2: 64 -> 4x16, concat, ELU ----
  gemm_mfma_kernel<128, false><<<g128, 256, 0, stream>>>(h1, wt2, xl, xr, N);
  node_agg_kernel<16, 0><<<nh2Blocks, 256, 0, stream>>>(
      xl, xr, a2, b2, row_ofs, csr_src, order, h2b, N);
  // ---- Layer 3: 64 -> 4x32, mean over heads; split-2 ----
  gemm_mfma_kernel<256, false><<<g256, 256, 0, stream>>>(h2b, wt3, xl, xr, N);
  node_agg_kernel<32, 1><<<nh2Blocks, 256, 0, stream>>>(
      xl, xr, a3, b3, row_ofs, csr_src, order, d_out, N);
}